// Round 1
// baseline (18374.579 us; speedup 1.0000x reference)
//
#include <hip/hip_runtime.h>

// GRU seq2seq, MI355X. Batch-parallel persistent decomposition:
//   256 blocks x 384 threads, each block owns 8 batch rows for ALL timesteps.
//   No grid sync, no workspace. h0/h1 in LDS, weights streamed from L2/L1.
// fp32 everywhere this round (correctness baseline; bf16/MFMA is next ladder step).

#define BT   8      // batch rows per block
#define NT   384    // threads per block (6 waves)
#define HD   128    // hidden size
#define G3   384    // 3*HD (gate dim)
#define TIN  336
#define TOUT 168
#define NFE  16     // input features
#define NB   256    // 2048 / BT

__device__ __forceinline__ float sigm(float x) {
    return 1.0f / (1.0f + __expf(-x));
}
__device__ __forceinline__ float tanh_fast(float x) {
    return 2.0f / (1.0f + __expf(-2.0f * x)) - 1.0f;
}

// OUT[r][j] = bias[j] + sum_k IN[r][k] * W[j*K + k],  r in [0,BT), j in [0,G3)
// Thread t: cols {2*(t%192), 2*(t%192)+1}, rows [4*(t/192), +4). All 8 accs in regs.
// IN reads are wave-uniform LDS broadcasts (threads in a wave share rgroup).
template<int K>
__device__ __forceinline__ void gemm_bt(const float* __restrict__ W,
                                        const float* __restrict__ bias,
                                        const float* in_lds, int in_stride,
                                        float* out_lds) {
    const int t  = threadIdx.x;
    const int c0 = (t % 192) * 2;
    const int r0 = (t / 192) * 4;
    const float* w0 = W + c0 * K;
    const float* w1 = w0 + K;
    float acc[4][2];
    const float b0v = bias[c0], b1v = bias[c0 + 1];
    #pragma unroll
    for (int r = 0; r < 4; ++r) { acc[r][0] = b0v; acc[r][1] = b1v; }
    #pragma unroll 4
    for (int k = 0; k < K; k += 4) {
        const float4 wa = *(const float4*)(w0 + k);
        const float4 wb = *(const float4*)(w1 + k);
        #pragma unroll
        for (int r = 0; r < 4; ++r) {
            const float4 iv = *(const float4*)(in_lds + (r0 + r) * in_stride + k);
            acc[r][0] = fmaf(iv.x, wa.x, acc[r][0]);
            acc[r][0] = fmaf(iv.y, wa.y, acc[r][0]);
            acc[r][0] = fmaf(iv.z, wa.z, acc[r][0]);
            acc[r][0] = fmaf(iv.w, wa.w, acc[r][0]);
            acc[r][1] = fmaf(iv.x, wb.x, acc[r][1]);
            acc[r][1] = fmaf(iv.y, wb.y, acc[r][1]);
            acc[r][1] = fmaf(iv.z, wb.z, acc[r][1]);
            acc[r][1] = fmaf(iv.w, wb.w, acc[r][1]);
        }
    }
    #pragma unroll
    for (int r = 0; r < 4; ++r) {
        *(float2*)(out_lds + (r0 + r) * G3 + c0) = make_float2(acc[r][0], acc[r][1]);
    }
}

// PyTorch GRU cell combine, gate order [r, z, n]:
//   r=sig(ir+hr); z=sig(iz+hz); n=tanh(in + r*hn); h' = (1-z)*n + z*h
__device__ __forceinline__ void gru_combine(float* h, const float* Gb, const float* Hgb) {
    for (int idx = threadIdx.x; idx < BT * HD; idx += NT) {
        const int r = idx >> 7;
        const int i = idx & (HD - 1);
        const float* g  = Gb  + r * G3;
        const float* hg = Hgb + r * G3;
        const float rg = sigm(g[i] + hg[i]);
        const float zg = sigm(g[HD + i] + hg[HD + i]);
        const float ng = tanh_fast(g[2 * HD + i] + rg * hg[2 * HD + i]);
        h[idx] = (1.0f - zg) * ng + zg * h[idx];
    }
}

extern "C" __global__ __launch_bounds__(NT)
void gru_seq2seq_kernel(
    const float* __restrict__ x,
    const float* __restrict__ eWih0, const float* __restrict__ eWhh0,
    const float* __restrict__ ebih0, const float* __restrict__ ebhh0,
    const float* __restrict__ eWih1, const float* __restrict__ eWhh1,
    const float* __restrict__ ebih1, const float* __restrict__ ebhh1,
    const float* __restrict__ dWih0, const float* __restrict__ dWhh0,
    const float* __restrict__ dbih0, const float* __restrict__ dbhh0,
    const float* __restrict__ dWih1, const float* __restrict__ dWhh1,
    const float* __restrict__ dbih1, const float* __restrict__ dbhh1,
    const float* __restrict__ fW1, const float* __restrict__ fb1,
    const float* __restrict__ fW2, const float* __restrict__ fb2,
    float* __restrict__ out)
{
    __shared__ float h0[BT][HD];
    __shared__ float h1[BT][HD];
    __shared__ float Gb[BT][G3];    // input-projection gates
    __shared__ float Hgb[BT][G3];   // hidden-projection gates
    __shared__ float xt[BT][NFE];
    __shared__ float inp[BT];
    __shared__ float hid[BT][64];

    const int b0 = blockIdx.x * BT;
    const int t  = threadIdx.x;

    for (int idx = t; idx < BT * HD; idx += NT) {
        (&h0[0][0])[idx] = 0.0f;
        (&h1[0][0])[idx] = 0.0f;
    }
    __syncthreads();

    // ---------------- encoder: 2-layer GRU, interleaved per timestep ----------------
    for (int step = 0; step < TIN; ++step) {
        if (t < BT * NFE) {
            const int r = t / NFE, f = t % NFE;
            xt[r][f] = x[((b0 + r) * TIN + step) * NFE + f];
        }
        __syncthreads();
        gemm_bt<NFE>(eWih0, ebih0, &xt[0][0], NFE, &Gb[0][0]);
        gemm_bt<HD>(eWhh0, ebhh0, &h0[0][0], HD, &Hgb[0][0]);
        __syncthreads();
        gru_combine(&h0[0][0], &Gb[0][0], &Hgb[0][0]);
        __syncthreads();
        gemm_bt<HD>(eWih1, ebih1, &h0[0][0], HD, &Gb[0][0]);
        gemm_bt<HD>(eWhh1, ebhh1, &h1[0][0], HD, &Hgb[0][0]);
        __syncthreads();
        gru_combine(&h1[0][0], &Gb[0][0], &Hgb[0][0]);
        __syncthreads();
    }

    // ---------------- autoregressive decoder ----------------
    if (t < BT) inp[t] = 0.0f;
    __syncthreads();

    for (int step = 0; step < TOUT; ++step) {
        // layer 0 input projection: inp is (BT,1), dWih0 is (G3,1) -> outer product
        for (int idx = t; idx < BT * G3; idx += NT) {
            const int r = idx / G3;
            const int j = idx - r * G3;
            Gb[0][idx] = fmaf(inp[r], dWih0[j], dbih0[j]);
        }
        gemm_bt<HD>(dWhh0, dbhh0, &h0[0][0], HD, &Hgb[0][0]);
        __syncthreads();
        gru_combine(&h0[0][0], &Gb[0][0], &Hgb[0][0]);
        __syncthreads();
        gemm_bt<HD>(dWih1, dbih1, &h0[0][0], HD, &Gb[0][0]);
        gemm_bt<HD>(dWhh1, dbhh1, &h1[0][0], HD, &Hgb[0][0]);
        __syncthreads();
        gru_combine(&h1[0][0], &Gb[0][0], &Hgb[0][0]);
        __syncthreads();

        // fc1: hid = relu(h1 @ fW1.T + fb1)   (BT x 64, K=128)
        for (int idx = t; idx < BT * 64; idx += NT) {
            const int r = idx >> 6, c = idx & 63;
            const float* w = fW1 + c * HD;
            float s = fb1[c];
            #pragma unroll 4
            for (int k = 0; k < HD; k += 4) {
                const float4 wv = *(const float4*)(w + k);
                const float4 hv = *(const float4*)(&h1[r][k]);
                s = fmaf(hv.x, wv.x, s);
                s = fmaf(hv.y, wv.y, s);
                s = fmaf(hv.z, wv.z, s);
                s = fmaf(hv.w, wv.w, s);
            }
            hid[r][c] = fmaxf(s, 0.0f);
        }
        __syncthreads();

        // fc2: pred = relu(hid @ fW2.T + fb2)  (BT x 1, K=64); feed back + store
        if (t < BT) {
            const int r = t;
            float s = fb2[0];
            #pragma unroll
            for (int k = 0; k < 64; k += 4) {
                const float4 wv = *(const float4*)(fW2 + k);
                const float4 hv = *(const float4*)(&hid[r][k]);
                s = fmaf(hv.x, wv.x, s);
                s = fmaf(hv.y, wv.y, s);
                s = fmaf(hv.z, wv.z, s);
                s = fmaf(hv.w, wv.w, s);
            }
            s = fmaxf(s, 0.0f);
            inp[r] = s;
            out[(b0 + r) * TOUT + step] = s;
        }
        __syncthreads();
    }
}

extern "C" void kernel_launch(void* const* d_in, const int* in_sizes, int n_in,
                              void* d_out, int out_size, void* d_ws, size_t ws_size,
                              hipStream_t stream) {
    const float* x     = (const float*)d_in[0];
    const float* eWih0 = (const float*)d_in[1];
    const float* eWhh0 = (const float*)d_in[2];
    const float* ebih0 = (const float*)d_in[3];
    const float* ebhh0 = (const float*)d_in[4];
    const float* eWih1 = (const float*)d_in[5];
    const float* eWhh1 = (const float*)d_in[6];
    const float* ebih1 = (const float*)d_in[7];
    const float* ebhh1 = (const float*)d_in[8];
    const float* dWih0 = (const float*)d_in[9];
    const float* dWhh0 = (const float*)d_in[10];
    const float* dbih0 = (const float*)d_in[11];
    const float* dbhh0 = (const float*)d_in[12];
    const float* dWih1 = (const float*)d_in[13];
    const float* dWhh1 = (const float*)d_in[14];
    const float* dbih1 = (const float*)d_in[15];
    const float* dbhh1 = (const float*)d_in[16];
    const float* fW1   = (const float*)d_in[17];
    const float* fb1   = (const float*)d_in[18];
    const float* fW2   = (const float*)d_in[19];
    const float* fb2   = (const float*)d_in[20];
    float* out = (float*)d_out;

    hipLaunchKernelGGL(gru_seq2seq_kernel, dim3(NB), dim3(NT), 0, stream,
                       x, eWih0, eWhh0, ebih0, ebhh0, eWih1, eWhh1, ebih1, ebhh1,
                       dWih0, dWhh0, dbih0, dbhh0, dWih1, dWhh1, dbih1, dbhh1,
                       fW1, fb1, fW2, fb2, out);
}

// Round 2
// 1941.638 us; speedup vs baseline: 9.4634x; 9.4634x over previous
//
#include <hip/hip_runtime.h>

// GRU seq2seq, MI355X gfx950. Round 2: MFMA-bf16 rewrite.
//   128 blocks x 768 threads (12 waves); each block owns 16 batch rows for all
//   504 timesteps. Weights pre-converted to bf16 MFMA B-fragment layout in d_ws
//   (prep kernel). h kept fp32 in registers; bf16 A-fragment copy in LDS.
//   mfma_f32_16x16x32_bf16: A[m=lane&15][k=quad*8+j], B[k=quad*8+j][n=lane&15],
//   C/D col=lane&15, row=quad*4+reg.  (layouts per cdna_hip_programming.md §3)

typedef unsigned short ushort_t;
typedef unsigned int uint_t;
typedef __attribute__((ext_vector_type(8))) short short8;
typedef __attribute__((ext_vector_type(4))) float f32x4;

#define BT   16     // batch rows per block
#define NT   768    // threads per block (12 waves)
#define HD   128
#define G3   384
#define GS   388    // padded LDS stride for gate buffers (2-way banks = free)
#define HS   68     // padded stride for fc1 output
#define TIN  336
#define TOUT 168
#define NFE  16
#define NB   128    // 2048 / BT

// d_ws fragment offsets, in 16B (short8) units. Hidden mats: 24 ntiles x 4 kf
// x 64 lanes = 6144 units each.
#define OFF_EWHH0 0
#define OFF_EWIH1 6144
#define OFF_EWHH1 12288
#define OFF_DWHH0 18432
#define OFF_DWIH1 24576
#define OFF_DWHH1 30720
#define OFF_EWIH0 36864   // 24 ntiles x 1 kf (K padded 16->32 with zeros)
#define OFF_FW1   38400   // 4 ntiles x 4 kf
#define WS_UNITS  39424   // ~616 KB total

__device__ __forceinline__ ushort_t f2bf(float f) {
    union { float f; uint_t u; } v; v.f = f;
    uint_t r = v.u + 0x7FFFu + ((v.u >> 16) & 1u);   // RNE
    return (ushort_t)(r >> 16);
}
__device__ __forceinline__ float sigm(float x) {
    return 1.0f / (1.0f + __expf(-x));
}
__device__ __forceinline__ float tanh_fast(float x) {
    return 2.0f / (1.0f + __expf(-2.0f * x)) - 1.0f;
}

// ---------------- prep: fp32 weights -> bf16 MFMA B-fragments in d_ws --------
// Fragment (nt,kf): lane L holds B[k=kf*32+(L>>4)*8+j][n=nt*16+(L&15)]
//                 = W[n][k+j], j=0..7, packed 8 bf16 = one uint4.
extern "C" __global__ __launch_bounds__(64)
void prep_kernel(const float* __restrict__ eWhh0, const float* __restrict__ eWih1,
                 const float* __restrict__ eWhh1, const float* __restrict__ dWhh0,
                 const float* __restrict__ dWih1, const float* __restrict__ dWhh1,
                 const float* __restrict__ eWih0, const float* __restrict__ fW1,
                 uint4* __restrict__ ws)
{
    const int g = blockIdx.x;           // frag id in [0, 616)
    const int L = threadIdx.x;          // lane
    const int n_lo = L & 15, q = L >> 4;

    const float* src; int n, kb, Ksrc, dst16;
    if (g < 576) {                      // six hidden 384x128 matrices
        const int m = g / 96, lf = g % 96;
        const float* hs[6] = {eWhh0, eWih1, eWhh1, dWhh0, dWih1, dWhh1};
        src = hs[m];
        const int nt = lf >> 2, kf = lf & 3;
        n = nt * 16 + n_lo; kb = kf * 32 + q * 8; Ksrc = 128;
        dst16 = m * 6144 + lf * 64 + L;
    } else if (g < 600) {               // eWih0: 384x16, K zero-padded to 32
        const int nt = g - 576;
        src = eWih0; n = nt * 16 + n_lo; kb = q * 8; Ksrc = 16;
        dst16 = OFF_EWIH0 + nt * 64 + L;
    } else {                            // fW1: 64x128
        const int lf = g - 600;
        src = fW1; n = (lf >> 2) * 16 + n_lo; kb = (lf & 3) * 32 + q * 8; Ksrc = 128;
        dst16 = OFF_FW1 + lf * 64 + L;
    }

    ushort_t h[8];
    #pragma unroll
    for (int j = 0; j < 8; ++j) {
        const int k = kb + j;
        h[j] = (k < Ksrc) ? f2bf(src[n * Ksrc + k]) : (ushort_t)0;
    }
    uint4 o;
    o.x = (uint_t)h[0] | ((uint_t)h[1] << 16);
    o.y = (uint_t)h[2] | ((uint_t)h[3] << 16);
    o.z = (uint_t)h[4] | ((uint_t)h[5] << 16);
    o.w = (uint_t)h[6] | ((uint_t)h[7] << 16);
    ws[dst16] = o;
}

// ---------------- main persistent kernel ------------------------------------

// One wave computes 2 n-tiles (nt = w*2, w*2+1) of C(16 x 384) = A(16x128) @ B.
// Writes C + bias into gate LDS buffer (stride GS).
template<int KF>
__device__ __forceinline__ void mfma_gemm(const short8* __restrict__ Wf,
                                          const float* __restrict__ bias,
                                          const ushort_t* Afrag,  // LDS frags
                                          float* outLds)
{
    const int t = threadIdx.x;
    const int L = t & 63, w = t >> 6;
    const int col = L & 15, q = L >> 4;
    #pragma unroll
    for (int t2 = 0; t2 < 2; ++t2) {
        const int nt = w * 2 + t2;
        f32x4 acc = {0.f, 0.f, 0.f, 0.f};
        #pragma unroll
        for (int kf = 0; kf < KF; ++kf) {
            const short8 a = *(const short8*)(Afrag + (kf * 64 + L) * 8);
            const short8 b = Wf[(nt * KF + kf) * 64 + L];
            acc = __builtin_amdgcn_mfma_f32_16x16x32_bf16(a, b, acc, 0, 0, 0);
        }
        const float bs = bias[nt * 16 + col];
        #pragma unroll
        for (int r_ = 0; r_ < 4; ++r_)
            outLds[(q * 4 + r_) * GS + nt * 16 + col] = acc[r_] + bs;
    }
}

// GRU combine: h' = (1-z)*n + z*h. h lives in thread registers (same thread
// owns the same elements every step); bf16 copy scattered to A-frag LDS.
__device__ __forceinline__ void gru_combine(const float* Gb_, const float* Hgb_,
                                            float* hreg, ushort_t* hfrag)
{
    const int t = threadIdx.x;
    #pragma unroll 3
    for (int c = 0; c < 3; ++c) {
        const int e = t + c * NT;
        if (e < BT * HD) {
            const int r = e >> 7, i = e & 127;
            const int base = r * GS + i;
            const float rg = sigm(Gb_[base] + Hgb_[base]);
            const float zg = sigm(Gb_[base + HD] + Hgb_[base + HD]);
            const float ng = tanh_fast(Gb_[base + 2 * HD] + rg * Hgb_[base + 2 * HD]);
            const float hn = (1.f - zg) * ng + zg * hreg[c];
            hreg[c] = hn;
            const int kf = i >> 5, qq = (i >> 3) & 3, j = i & 7;
            hfrag[((kf * 64) + qq * 16 + r) * 8 + j] = f2bf(hn);
        }
    }
}

extern "C" __global__ __launch_bounds__(NT)
void gru_seq2seq_kernel(
    const float* __restrict__ x,
    const float* __restrict__ ebih0, const float* __restrict__ ebhh0,
    const float* __restrict__ ebih1, const float* __restrict__ ebhh1,
    const float* __restrict__ dWih0, const float* __restrict__ dbih0,
    const float* __restrict__ dbhh0,
    const float* __restrict__ dbih1, const float* __restrict__ dbhh1,
    const float* __restrict__ fb1, const float* __restrict__ fW2,
    const float* __restrict__ fb2,
    const short8* __restrict__ wf,   // d_ws fragments
    float* __restrict__ out)
{
    __shared__ ushort_t h0frag[4 * 64 * 8];   // 4 kf x 64 lanes x 8 bf16
    __shared__ ushort_t h1frag[4 * 64 * 8];
    __shared__ ushort_t xfrag[2][512];        // double-buffered, kf=0 only
    __shared__ float Gb[BT * GS];
    __shared__ float Hgb[BT * GS];
    __shared__ float hid[BT * HS];
    __shared__ float inp[BT];

    const int b0 = blockIdx.x * BT;
    const int t  = threadIdx.x;

    // zero h frags (h=0) and xfrag (k>=16 pad must stay zero)
    for (int i = t; i < 2048; i += NT) { h0frag[i] = 0; h1frag[i] = 0; }
    for (int i = t; i < 1024; i += NT) { (&xfrag[0][0])[i] = 0; }

    float h0r[3] = {0.f, 0.f, 0.f};
    float h1r[3] = {0.f, 0.f, 0.f};

    // x prefetch for step 0 (first 256 threads: one element each)
    const int xr = t >> 4, xf = t & 15;
    float xv = 0.f;
    if (t < 256) xv = x[((b0 + xr) * TIN + 0) * NFE + xf];
    __syncthreads();

    // ---------------- encoder ----------------
    for (int s = 0; s < TIN; ++s) {
        // scatter x into A-frag layout (lane = (f>>3)*16 + r, j = f&7)
        if (t < 256) {
            xfrag[s & 1][(((xf >> 3) * 16) + xr) * 8 + (xf & 7)] = f2bf(xv);
            if (s + 1 < TIN) xv = x[((b0 + xr) * TIN + s + 1) * NFE + xf];
        }
        __syncthreads();
        mfma_gemm<1>(wf + OFF_EWIH0, ebih0, &xfrag[s & 1][0], Gb);
        mfma_gemm<4>(wf + OFF_EWHH0, ebhh0, h0frag, Hgb);
        __syncthreads();
        gru_combine(Gb, Hgb, h0r, h0frag);
        __syncthreads();
        mfma_gemm<4>(wf + OFF_EWIH1, ebih1, h0frag, Gb);
        mfma_gemm<4>(wf + OFF_EWHH1, ebhh1, h1frag, Hgb);
        __syncthreads();
        gru_combine(Gb, Hgb, h1r, h1frag);
        // loop-top sync covers h1frag/Gb/Hgb reuse
        __syncthreads();
    }

    if (t < BT) inp[t] = 0.f;
    __syncthreads();

    // ---------------- decoder ----------------
    for (int s = 0; s < TOUT; ++s) {
        // P1: layer-0 input gates = outer(inp, dWih0) + bias; hidden gates MFMA
        for (int idx = t; idx < BT * G3; idx += NT) {
            const int r = idx / G3, j = idx - r * G3;
            Gb[r * GS + j] = fmaf(inp[r], dWih0[j], dbih0[j]);
        }
        mfma_gemm<4>(wf + OFF_DWHH0, dbhh0, h0frag, Hgb);
        __syncthreads();
        gru_combine(Gb, Hgb, h0r, h0frag);
        __syncthreads();
        mfma_gemm<4>(wf + OFF_DWIH1, dbih1, h0frag, Gb);
        mfma_gemm<4>(wf + OFF_DWHH1, dbhh1, h1frag, Hgb);
        __syncthreads();
        gru_combine(Gb, Hgb, h1r, h1frag);
        __syncthreads();

        // P5: fc1 = relu(h1 @ fW1.T + fb1) -> hid  (4 n-tiles, waves 0-3)
        {
            const int L = t & 63, w = t >> 6;
            if (w < 4) {
                const int col = L & 15, q = L >> 4;
                const int nt = w;
                f32x4 acc = {0.f, 0.f, 0.f, 0.f};
                #pragma unroll
                for (int kf = 0; kf < 4; ++kf) {
                    const short8 a = *(const short8*)(h1frag + (kf * 64 + L) * 8);
                    const short8 b = wf[OFF_FW1 + (nt * 4 + kf) * 64 + L];
                    acc = __builtin_amdgcn_mfma_f32_16x16x32_bf16(a, b, acc, 0, 0, 0);
                }
                const float bs = fb1[nt * 16 + col];
                #pragma unroll
                for (int r_ = 0; r_ < 4; ++r_)
                    hid[(q * 4 + r_) * HS + nt * 16 + col] = fmaxf(acc[r_] + bs, 0.f);
            }
        }
        __syncthreads();

        // P6: fc2 = relu(hid @ fW2.T + fb2), feedback + store (wave 0)
        if (t < 64) {
            const int r = t >> 2, kq = t & 3;
            const float* row = hid + r * HS + kq * 16;
            float s_ = 0.f;
            #pragma unroll
            for (int k4 = 0; k4 < 4; ++k4) {
                const float4 hv = *(const float4*)(row + k4 * 4);
                const float4 wv = *(const float4*)(fW2 + kq * 16 + k4 * 4);
                s_ = fmaf(hv.x, wv.x, s_);
                s_ = fmaf(hv.y, wv.y, s_);
                s_ = fmaf(hv.z, wv.z, s_);
                s_ = fmaf(hv.w, wv.w, s_);
            }
            s_ += __shfl_xor(s_, 1, 64);
            s_ += __shfl_xor(s_, 2, 64);
            if (kq == 0) {
                const float v = fmaxf(s_ + fb2[0], 0.f);
                inp[r] = v;
                out[(b0 + r) * TOUT + s] = v;
            }
        }
        __syncthreads();
    }
}

extern "C" void kernel_launch(void* const* d_in, const int* in_sizes, int n_in,
                              void* d_out, int out_size, void* d_ws, size_t ws_size,
                              hipStream_t stream) {
    const float* x     = (const float*)d_in[0];
    const float* eWih0 = (const float*)d_in[1];
    const float* eWhh0 = (const float*)d_in[2];
    const float* ebih0 = (const float*)d_in[3];
    const float* ebhh0 = (const float*)d_in[4];
    const float* eWih1 = (const float*)d_in[5];
    const float* eWhh1 = (const float*)d_in[6];
    const float* ebih1 = (const float*)d_in[7];
    const float* ebhh1 = (const float*)d_in[8];
    const float* dWih0 = (const float*)d_in[9];
    const float* dWhh0 = (const float*)d_in[10];
    const float* dbih0 = (const float*)d_in[11];
    const float* dbhh0 = (const float*)d_in[12];
    const float* dWih1 = (const float*)d_in[13];
    const float* dWhh1 = (const float*)d_in[14];
    const float* dbih1 = (const float*)d_in[15];
    const float* dbhh1 = (const float*)d_in[16];
    const float* fW1   = (const float*)d_in[17];
    const float* fb1   = (const float*)d_in[18];
    const float* fW2   = (const float*)d_in[19];
    const float* fb2   = (const float*)d_in[20];
    float* out = (float*)d_out;

    hipLaunchKernelGGL(prep_kernel, dim3(616), dim3(64), 0, stream,
                       eWhh0, eWih1, eWhh1, dWhh0, dWih1, dWhh1, eWih0, fW1,
                       (uint4*)d_ws);
    hipLaunchKernelGGL(gru_seq2seq_kernel, dim3(NB), dim3(NT), 0, stream,
                       x, ebih0, ebhh0, ebih1, ebhh1,
                       dWih0, dbih0, dbhh0, dbih1, dbhh1,
                       fb1, fW2, fb2,
                       (const short8*)d_ws, out);
}